// Round 1
// baseline (1585.847 us; speedup 1.0000x reference)
//
#include <hip/hip_runtime.h>
#include <hip/hip_bf16.h>

#define N_NODES 50000
#define N_EDGES 800000
#define HDIM 128
#define NGRAPH 512
#define NCLS 10
#define BN_EPS 1e-5f

// ---------------------------------------------------------------------------
// deg[dst]++ over edges, cnt[batch]++ over nodes (atomics, one pass)
// ---------------------------------------------------------------------------
__global__ __launch_bounds__(256) void deg_count(const int* __restrict__ dst,
                                                 const int* __restrict__ batch,
                                                 float* __restrict__ deg,
                                                 float* __restrict__ cnt,
                                                 int ne, int n)
{
    int i = blockIdx.x * 256 + threadIdx.x;
    if (i < ne) atomicAdd(&deg[dst[i]], 1.0f);
    if (i < n)  atomicAdd(&cnt[batch[i]], 1.0f);
}

__global__ __launch_bounds__(256) void rsqrt_deg(float* __restrict__ deg, int n)
{
    int i = blockIdx.x * 256 + threadIdx.x;
    if (i < n) deg[i] = rsqrtf(deg[i] + 1.0f);   // deg includes self-loop +1
}

// ---------------------------------------------------------------------------
// Y[n][0:128] = X[n][0:128] @ W[128][128], fp32 (no fp32 MFMA on CDNA4).
// 32 rows/block, 256 threads, 4x4 register tile, W+X staged in LDS.
// ---------------------------------------------------------------------------
__global__ __launch_bounds__(256) void gemm_nk128(const float* __restrict__ X,
                                                  const float* __restrict__ W,
                                                  float* __restrict__ Y, int nrows)
{
    __shared__ float xs[32][36];    // +4 pad keeps 16B alignment, breaks pow2 stride
    __shared__ float ws[32][128];
    const int t   = threadIdx.x;
    const int row0 = blockIdx.x * 32;
    const int tx  = t & 31;         // col group: cols 4*tx..4*tx+3
    const int ty  = t >> 5;         // row group: rows 4*ty..4*ty+3

    float acc[4][4];
    #pragma unroll
    for (int i = 0; i < 4; ++i)
        #pragma unroll
        for (int j = 0; j < 4; ++j) acc[i][j] = 0.f;

    const int lr = t >> 3;          // x-stage row 0..31
    const int lk = (t & 7) << 2;    // x-stage k offset
    const int wr = t >> 5;          // w-stage row base
    const int wc = (t & 31) << 2;   // w-stage col

    for (int k0 = 0; k0 < 128; k0 += 32) {
        float4 xv = make_float4(0.f, 0.f, 0.f, 0.f);
        int grow = row0 + lr;
        if (grow < nrows) xv = *(const float4*)(X + (size_t)grow * HDIM + k0 + lk);
        xs[lr][lk] = xv.x; xs[lr][lk + 1] = xv.y; xs[lr][lk + 2] = xv.z; xs[lr][lk + 3] = xv.w;
        #pragma unroll
        for (int i = 0; i < 4; ++i) {
            int kk = wr + i * 8;
            *(float4*)&ws[kk][wc] = *(const float4*)(W + (size_t)(k0 + kk) * HDIM + wc);
        }
        __syncthreads();
        #pragma unroll
        for (int kk = 0; kk < 32; kk += 4) {
            float4 wv[4];
            #pragma unroll
            for (int j = 0; j < 4; ++j) wv[j] = *(const float4*)&ws[kk + j][tx << 2];
            #pragma unroll
            for (int i = 0; i < 4; ++i) {
                float4 xr = *(const float4*)&xs[ty * 4 + i][kk];
                acc[i][0] += xr.x * wv[0].x; acc[i][1] += xr.x * wv[0].y;
                acc[i][2] += xr.x * wv[0].z; acc[i][3] += xr.x * wv[0].w;
                acc[i][0] += xr.y * wv[1].x; acc[i][1] += xr.y * wv[1].y;
                acc[i][2] += xr.y * wv[1].z; acc[i][3] += xr.y * wv[1].w;
                acc[i][0] += xr.z * wv[2].x; acc[i][1] += xr.z * wv[2].y;
                acc[i][2] += xr.z * wv[2].z; acc[i][3] += xr.z * wv[2].w;
                acc[i][0] += xr.w * wv[3].x; acc[i][1] += xr.w * wv[3].y;
                acc[i][2] += xr.w * wv[3].z; acc[i][3] += xr.w * wv[3].w;
            }
        }
        __syncthreads();
    }
    #pragma unroll
    for (int i = 0; i < 4; ++i) {
        int grow = row0 + ty * 4 + i;
        if (grow < nrows)
            *(float4*)(Y + (size_t)grow * HDIM + (tx << 2)) =
                make_float4(acc[i][0], acc[i][1], acc[i][2], acc[i][3]);
    }
}

// ---------------------------------------------------------------------------
// Edge aggregation: out[dst] += h[src] * dis[src]*dis[dst].  One wave/edge,
// lane handles 2 channels (coalesced 512B row read), fp32 atomics to L2.
// ---------------------------------------------------------------------------
__global__ __launch_bounds__(256) void agg_edges(const float* __restrict__ h,
                                                 const int* __restrict__ src,
                                                 const int* __restrict__ dst,
                                                 const float* __restrict__ dis,
                                                 float* __restrict__ out, int ne)
{
    int w    = (blockIdx.x * 256 + threadIdx.x) >> 6;
    int lane = threadIdx.x & 63;
    if (w >= ne) return;
    int s = src[w], d = dst[w];
    float nm = dis[s] * dis[d];
    float2 v = *(const float2*)(h + (size_t)s * HDIM + lane * 2);
    float* o = out + (size_t)d * HDIM + lane * 2;
    atomicAdd(o,     v.x * nm);
    atomicAdd(o + 1, v.y * nm);
}

// ---------------------------------------------------------------------------
// agg += h*dis^2 (self loop) + b; then BN(eval) + ReLU, in place on agg.
// ---------------------------------------------------------------------------
__global__ __launch_bounds__(256) void post_bn_relu(float* __restrict__ agg,
                                                    const float* __restrict__ h,
                                                    const float* __restrict__ dis,
                                                    const float* __restrict__ b,
                                                    const float* __restrict__ gamma,
                                                    const float* __restrict__ beta,
                                                    const float* __restrict__ mean,
                                                    const float* __restrict__ var,
                                                    int n)
{
    int i = blockIdx.x * 256 + threadIdx.x;
    if (i >= n * 32) return;
    int node = i >> 5;
    int c    = (i & 31) << 2;
    float dd = dis[node]; dd *= dd;
    float4 a  = *(float4*)(agg + (size_t)node * HDIM + c);
    float4 hv = *(const float4*)(h + (size_t)node * HDIM + c);
    float av[4] = {a.x, a.y, a.z, a.w};
    float hh[4] = {hv.x, hv.y, hv.z, hv.w};
    float o[4];
    #pragma unroll
    for (int j = 0; j < 4; ++j) {
        float val = av[j] + hh[j] * dd + b[c + j];
        float sc  = gamma[c + j] * rsqrtf(var[c + j] + BN_EPS);
        float r   = (val - mean[c + j]) * sc + beta[c + j];
        o[j] = fmaxf(r, 0.f);
    }
    *(float4*)(agg + (size_t)node * HDIM + c) = make_float4(o[0], o[1], o[2], o[3]);
}

// ---------------------------------------------------------------------------
// Pool: sums[batch[n]][c] += h[n][c].  batch is sorted -> per-block local
// accumulation over 32 consecutive nodes, atomic only at segment boundaries.
// ---------------------------------------------------------------------------
__global__ __launch_bounds__(128) void pool_sum(const float* __restrict__ h,
                                                const int* __restrict__ batch,
                                                float* __restrict__ sums, int n)
{
    int c  = threadIdx.x;          // channel 0..127
    int n0 = blockIdx.x * 32;
    if (n0 >= n) return;
    int nend = min(n0 + 32, n);
    int curg = batch[n0];
    float acc = 0.f;
    for (int i = n0; i < nend; ++i) {
        int g   = batch[i];                       // uniform across block -> broadcast
        float v = h[(size_t)i * HDIM + c];
        if (g != curg) {
            atomicAdd(&sums[(size_t)curg * HDIM + c], acc);
            acc = 0.f; curg = g;
        }
        acc += v;
    }
    atomicAdd(&sums[(size_t)curg * HDIM + c], acc);
}

// ---------------------------------------------------------------------------
// out[g][c] = (sums[g]/max(cnt[g],1)) . Wlin[:,c] + blin[c]
// ---------------------------------------------------------------------------
__global__ __launch_bounds__(128) void final_lin(const float* __restrict__ sums,
                                                 const float* __restrict__ cnt,
                                                 const float* __restrict__ Wlin,
                                                 const float* __restrict__ blin,
                                                 float* __restrict__ out)
{
    __shared__ float red[NCLS][2];
    int g = blockIdx.x;
    int t = threadIdx.x;           // 0..127 = k index
    float ic = 1.f / fmaxf(cnt[g], 1.f);
    float v  = sums[(size_t)g * HDIM + t] * ic;
    float p[NCLS];
    #pragma unroll
    for (int c = 0; c < NCLS; ++c) p[c] = v * Wlin[t * NCLS + c];
    #pragma unroll
    for (int c = 0; c < NCLS; ++c) {
        float x = p[c];
        for (int off = 32; off > 0; off >>= 1) x += __shfl_down(x, off);
        if ((t & 63) == 0) red[c][t >> 6] = x;
    }
    __syncthreads();
    if (t < NCLS) out[g * NCLS + t] = red[t][0] + red[t][1] + blin[t];
}

// ---------------------------------------------------------------------------
extern "C" void kernel_launch(void* const* d_in, const int* in_sizes, int n_in,
                              void* d_out, int out_size, void* d_ws, size_t ws_size,
                              hipStream_t stream)
{
    const float* x     = (const float*)d_in[0];
    const int*   ei    = (const int*)d_in[1];
    const int*   srcp  = ei;
    const int*   dstp  = ei + N_EDGES;
    const int*   batch = (const int*)d_in[2];
    const float* W1    = (const float*)d_in[3];
    const float* b1    = (const float*)d_in[4];
    const float* g1    = (const float*)d_in[5];
    const float* be1   = (const float*)d_in[6];
    const float* m1    = (const float*)d_in[7];
    const float* v1    = (const float*)d_in[8];
    const float* W2    = (const float*)d_in[9];
    const float* b2    = (const float*)d_in[10];
    const float* g2    = (const float*)d_in[11];
    const float* be2   = (const float*)d_in[12];
    const float* m2    = (const float*)d_in[13];
    const float* v2    = (const float*)d_in[14];
    const float* Wlin  = (const float*)d_in[15];
    const float* blin  = (const float*)d_in[16];
    float*       out   = (float*)d_out;

    // workspace layout (floats): bufA | bufB | dis | cnt | sums   (~49.3 MiB)
    float* bufA = (float*)d_ws;
    float* bufB = bufA + (size_t)N_NODES * HDIM;
    float* dis  = bufB + (size_t)N_NODES * HDIM;
    float* cnt  = dis + N_NODES;
    float* sums = cnt + NGRAPH;

    const size_t hbytes = (size_t)N_NODES * HDIM * sizeof(float);

    // zero dis/cnt/sums in one contiguous memset
    hipMemsetAsync(dis, 0, (N_NODES + NGRAPH + (size_t)NGRAPH * HDIM) * sizeof(float), stream);

    deg_count<<<(N_EDGES + 255) / 256, 256, 0, stream>>>(dstp, batch, dis, cnt, N_EDGES, N_NODES);
    rsqrt_deg<<<(N_NODES + 255) / 256, 256, 0, stream>>>(dis, N_NODES);

    const int gemm_blocks = (N_NODES + 31) / 32;

    // ---- layer 1 ----
    gemm_nk128<<<gemm_blocks, 256, 0, stream>>>(x, W1, bufA, N_NODES);
    hipMemsetAsync(bufB, 0, hbytes, stream);
    agg_edges<<<(N_EDGES + 3) / 4, 256, 0, stream>>>(bufA, srcp, dstp, dis, bufB, N_EDGES);
    post_bn_relu<<<(N_NODES * 32 + 255) / 256, 256, 0, stream>>>(bufB, bufA, dis,
                                                                 b1, g1, be1, m1, v1, N_NODES);
    // ---- layer 2 ----
    gemm_nk128<<<gemm_blocks, 256, 0, stream>>>(bufB, W2, bufA, N_NODES);
    hipMemsetAsync(bufB, 0, hbytes, stream);
    agg_edges<<<(N_EDGES + 3) / 4, 256, 0, stream>>>(bufA, srcp, dstp, dis, bufB, N_EDGES);
    post_bn_relu<<<(N_NODES * 32 + 255) / 256, 256, 0, stream>>>(bufB, bufA, dis,
                                                                 b2, g2, be2, m2, v2, N_NODES);
    // ---- pool + head ----
    pool_sum<<<(N_NODES + 31) / 32, 128, 0, stream>>>(bufB, batch, sums, N_NODES);
    final_lin<<<NGRAPH, 128, 0, stream>>>(sums, cnt, Wlin, blin, out);
}

// Round 2
// 557.642 us; speedup vs baseline: 2.8438x; 2.8438x over previous
//
#include <hip/hip_runtime.h>
#include <hip/hip_bf16.h>

#define N_NODES 50000
#define N_EDGES 800000
#define HDIM 128
#define NGRAPH 512
#define NCLS 10
#define BN_EPS 1e-5f

// ---------------------------------------------------------------------------
// deg_i[dst]++ (int) over edges; cnt[batch]++ (float) over nodes.
// ---------------------------------------------------------------------------
__global__ __launch_bounds__(256) void deg_count(const int* __restrict__ dst,
                                                 const int* __restrict__ batch,
                                                 int* __restrict__ deg_i,
                                                 float* __restrict__ cnt,
                                                 int ne, int n)
{
    int i = blockIdx.x * 256 + threadIdx.x;
    if (i < ne) atomicAdd(&deg_i[dst[i]], 1);
    if (i < n)  atomicAdd(&cnt[batch[i]], 1.0f);
}

// dis[i] = rsqrt(deg_i[i] + 1)   (+1 = self loop)
__global__ __launch_bounds__(256) void rsqrt_deg(const int* __restrict__ deg_i,
                                                 float* __restrict__ dis, int n)
{
    int i = blockIdx.x * 256 + threadIdx.x;
    if (i < n) dis[i] = rsqrtf((float)deg_i[i] + 1.0f);
}

// ---------------------------------------------------------------------------
// Exclusive scan of deg_i[0..n) -> row_ptr[0..n], single block of 1024.
// Each thread owns a contiguous chunk; Hillis-Steele scan of chunk sums.
// ---------------------------------------------------------------------------
__global__ __launch_bounds__(1024) void scan_deg(const int* __restrict__ deg_i,
                                                 int* __restrict__ row_ptr, int n)
{
    __shared__ int lds[1024];
    const int t = threadIdx.x;
    const int chunk = (n + 1023) >> 10;
    const int i0 = t * chunk;
    int s = 0;
    for (int j = 0; j < chunk; ++j) {
        int i = i0 + j;
        if (i < n) s += deg_i[i];
    }
    lds[t] = s;
    __syncthreads();
    #pragma unroll
    for (int off = 1; off < 1024; off <<= 1) {
        int v = (t >= off) ? lds[t - off] : 0;
        __syncthreads();
        lds[t] += v;
        __syncthreads();
    }
    int run = lds[t] - s;               // exclusive base for this chunk
    for (int j = 0; j < chunk; ++j) {
        int i = i0 + j;
        if (i < n) { row_ptr[i] = run; run += deg_i[i]; }
    }
    if (t == 1023) row_ptr[n] = lds[1023];
}

// ---------------------------------------------------------------------------
// Scatter edges into dst-sorted order: esrc[row_ptr[d] + cursor[d]++] = src.
// ---------------------------------------------------------------------------
__global__ __launch_bounds__(256) void scatter_edges(const int* __restrict__ src,
                                                     const int* __restrict__ dst,
                                                     const int* __restrict__ row_ptr,
                                                     int* __restrict__ cursor,
                                                     int* __restrict__ esrc, int ne)
{
    int e = blockIdx.x * 256 + threadIdx.x;
    if (e >= ne) return;
    int d = dst[e];
    int pos = row_ptr[d] + atomicAdd(&cursor[d], 1);
    esrc[pos] = src[e];
}

// ---------------------------------------------------------------------------
// Y[n][0:128] = X[n][0:128] @ W[128][128], fp32 (no fp32 MFMA on CDNA4).
// 32 rows/block, 256 threads, 4x4 register tile, W+X staged in LDS.
// ---------------------------------------------------------------------------
__global__ __launch_bounds__(256) void gemm_nk128(const float* __restrict__ X,
                                                  const float* __restrict__ W,
                                                  float* __restrict__ Y, int nrows)
{
    __shared__ float xs[32][36];
    __shared__ float ws[32][128];
    const int t   = threadIdx.x;
    const int row0 = blockIdx.x * 32;
    const int tx  = t & 31;
    const int ty  = t >> 5;

    float acc[4][4];
    #pragma unroll
    for (int i = 0; i < 4; ++i)
        #pragma unroll
        for (int j = 0; j < 4; ++j) acc[i][j] = 0.f;

    const int lr = t >> 3;
    const int lk = (t & 7) << 2;
    const int wr = t >> 5;
    const int wc = (t & 31) << 2;

    for (int k0 = 0; k0 < 128; k0 += 32) {
        float4 xv = make_float4(0.f, 0.f, 0.f, 0.f);
        int grow = row0 + lr;
        if (grow < nrows) xv = *(const float4*)(X + (size_t)grow * HDIM + k0 + lk);
        xs[lr][lk] = xv.x; xs[lr][lk + 1] = xv.y; xs[lr][lk + 2] = xv.z; xs[lr][lk + 3] = xv.w;
        #pragma unroll
        for (int i = 0; i < 4; ++i) {
            int kk = wr + i * 8;
            *(float4*)&ws[kk][wc] = *(const float4*)(W + (size_t)(k0 + kk) * HDIM + wc);
        }
        __syncthreads();
        #pragma unroll
        for (int kk = 0; kk < 32; kk += 4) {
            float4 wv[4];
            #pragma unroll
            for (int j = 0; j < 4; ++j) wv[j] = *(const float4*)&ws[kk + j][tx << 2];
            #pragma unroll
            for (int i = 0; i < 4; ++i) {
                float4 xr = *(const float4*)&xs[ty * 4 + i][kk];
                acc[i][0] += xr.x * wv[0].x; acc[i][1] += xr.x * wv[0].y;
                acc[i][2] += xr.x * wv[0].z; acc[i][3] += xr.x * wv[0].w;
                acc[i][0] += xr.y * wv[1].x; acc[i][1] += xr.y * wv[1].y;
                acc[i][2] += xr.y * wv[1].z; acc[i][3] += xr.y * wv[1].w;
                acc[i][0] += xr.z * wv[2].x; acc[i][1] += xr.z * wv[2].y;
                acc[i][2] += xr.z * wv[2].z; acc[i][3] += xr.z * wv[2].w;
                acc[i][0] += xr.w * wv[3].x; acc[i][1] += xr.w * wv[3].y;
                acc[i][2] += xr.w * wv[3].z; acc[i][3] += xr.w * wv[3].w;
            }
        }
        __syncthreads();
    }
    #pragma unroll
    for (int i = 0; i < 4; ++i) {
        int grow = row0 + ty * 4 + i;
        if (grow < nrows)
            *(float4*)(Y + (size_t)grow * HDIM + (tx << 2)) =
                make_float4(acc[i][0], acc[i][1], acc[i][2], acc[i][3]);
    }
}

// ---------------------------------------------------------------------------
// CSR gather + self-loop + bias + BN(eval) + ReLU, fused.
// One wave per dst node; lane handles channels 2*lane, 2*lane+1.
// ---------------------------------------------------------------------------
__global__ __launch_bounds__(256) void gather_bn_relu(const float* __restrict__ h,
                                                      const int* __restrict__ esrc,
                                                      const int* __restrict__ row_ptr,
                                                      const float* __restrict__ dis,
                                                      const float* __restrict__ b,
                                                      const float* __restrict__ gamma,
                                                      const float* __restrict__ beta,
                                                      const float* __restrict__ mean,
                                                      const float* __restrict__ var,
                                                      float* __restrict__ out, int n)
{
    int node = blockIdx.x * 4 + (threadIdx.x >> 6);
    int lane = threadIdx.x & 63;
    if (node >= n) return;
    const int e0 = row_ptr[node], e1 = row_ptr[node + 1];
    const float dd = dis[node];
    const int c = lane * 2;

    float ax = 0.f, ay = 0.f;
    for (int e = e0; e < e1; ++e) {
        int s = esrc[e];
        float nm = dis[s] * dd;
        float2 v = *(const float2*)(h + (size_t)s * HDIM + c);
        ax += v.x * nm;
        ay += v.y * nm;
    }
    // self-loop term: h[node] * dd^2
    float2 hv = *(const float2*)(h + (size_t)node * HDIM + c);
    ax += hv.x * dd * dd;
    ay += hv.y * dd * dd;
    // bias + BN + ReLU
    float sx = gamma[c]     * rsqrtf(var[c]     + BN_EPS);
    float sy = gamma[c + 1] * rsqrtf(var[c + 1] + BN_EPS);
    float rx = (ax + b[c]     - mean[c])     * sx + beta[c];
    float ry = (ay + b[c + 1] - mean[c + 1]) * sy + beta[c + 1];
    float2 o = make_float2(fmaxf(rx, 0.f), fmaxf(ry, 0.f));
    *(float2*)(out + (size_t)node * HDIM + c) = o;
}

// ---------------------------------------------------------------------------
// Pool: sums[batch[n]][c] += h[n][c]; batch sorted -> segment-local acc.
// ---------------------------------------------------------------------------
__global__ __launch_bounds__(128) void pool_sum(const float* __restrict__ h,
                                                const int* __restrict__ batch,
                                                float* __restrict__ sums, int n)
{
    int c  = threadIdx.x;
    int n0 = blockIdx.x * 32;
    if (n0 >= n) return;
    int nend = min(n0 + 32, n);
    int curg = batch[n0];
    float acc = 0.f;
    for (int i = n0; i < nend; ++i) {
        int g   = batch[i];
        float v = h[(size_t)i * HDIM + c];
        if (g != curg) {
            atomicAdd(&sums[(size_t)curg * HDIM + c], acc);
            acc = 0.f; curg = g;
        }
        acc += v;
    }
    atomicAdd(&sums[(size_t)curg * HDIM + c], acc);
}

// ---------------------------------------------------------------------------
// out[g][c] = (sums[g]/max(cnt[g],1)) . Wlin[:,c] + blin[c]
// ---------------------------------------------------------------------------
__global__ __launch_bounds__(128) void final_lin(const float* __restrict__ sums,
                                                 const float* __restrict__ cnt,
                                                 const float* __restrict__ Wlin,
                                                 const float* __restrict__ blin,
                                                 float* __restrict__ out)
{
    __shared__ float red[NCLS][2];
    int g = blockIdx.x;
    int t = threadIdx.x;
    float ic = 1.f / fmaxf(cnt[g], 1.f);
    float v  = sums[(size_t)g * HDIM + t] * ic;
    float p[NCLS];
    #pragma unroll
    for (int c = 0; c < NCLS; ++c) p[c] = v * Wlin[t * NCLS + c];
    #pragma unroll
    for (int c = 0; c < NCLS; ++c) {
        float x = p[c];
        for (int off = 32; off > 0; off >>= 1) x += __shfl_down(x, off);
        if ((t & 63) == 0) red[c][t >> 6] = x;
    }
    __syncthreads();
    if (t < NCLS) out[g * NCLS + t] = red[t][0] + red[t][1] + blin[t];
}

// ---------------------------------------------------------------------------
extern "C" void kernel_launch(void* const* d_in, const int* in_sizes, int n_in,
                              void* d_out, int out_size, void* d_ws, size_t ws_size,
                              hipStream_t stream)
{
    const float* x     = (const float*)d_in[0];
    const int*   ei    = (const int*)d_in[1];
    const int*   srcp  = ei;
    const int*   dstp  = ei + N_EDGES;
    const int*   batch = (const int*)d_in[2];
    const float* W1    = (const float*)d_in[3];
    const float* b1    = (const float*)d_in[4];
    const float* g1    = (const float*)d_in[5];
    const float* be1   = (const float*)d_in[6];
    const float* m1    = (const float*)d_in[7];
    const float* v1    = (const float*)d_in[8];
    const float* W2    = (const float*)d_in[9];
    const float* b2    = (const float*)d_in[10];
    const float* g2    = (const float*)d_in[11];
    const float* be2   = (const float*)d_in[12];
    const float* m2    = (const float*)d_in[13];
    const float* v2    = (const float*)d_in[14];
    const float* Wlin  = (const float*)d_in[15];
    const float* blin  = (const float*)d_in[16];
    float*       out   = (float*)d_out;

    // workspace layout (floats/ints):
    // bufA | bufB | esrc | row_ptr | dis | deg_i | cnt | sums      (~55 MiB)
    float* bufA    = (float*)d_ws;
    float* bufB    = bufA + (size_t)N_NODES * HDIM;
    int*   esrc    = (int*)(bufB + (size_t)N_NODES * HDIM);
    int*   row_ptr = esrc + N_EDGES;
    float* dis     = (float*)(row_ptr + N_NODES + 1);
    int*   deg_i   = (int*)(dis + N_NODES);
    float* cnt     = (float*)(deg_i + N_NODES);
    float* sums    = cnt + NGRAPH;

    // zero deg_i | cnt | sums in one contiguous memset
    hipMemsetAsync(deg_i, 0,
                   (N_NODES + NGRAPH + (size_t)NGRAPH * HDIM) * sizeof(float), stream);

    // ---- CSR build ----
    deg_count<<<(N_EDGES + 255) / 256, 256, 0, stream>>>(dstp, batch, deg_i, cnt,
                                                         N_EDGES, N_NODES);
    rsqrt_deg<<<(N_NODES + 255) / 256, 256, 0, stream>>>(deg_i, dis, N_NODES);
    scan_deg<<<1, 1024, 0, stream>>>(deg_i, row_ptr, N_NODES);
    hipMemsetAsync(deg_i, 0, N_NODES * sizeof(int), stream);   // reuse as cursor
    scatter_edges<<<(N_EDGES + 255) / 256, 256, 0, stream>>>(srcp, dstp, row_ptr,
                                                             deg_i, esrc, N_EDGES);

    const int gemm_blocks   = (N_NODES + 31) / 32;
    const int gather_blocks = (N_NODES + 3) / 4;

    // ---- layer 1 ----
    gemm_nk128<<<gemm_blocks, 256, 0, stream>>>(x, W1, bufA, N_NODES);
    gather_bn_relu<<<gather_blocks, 256, 0, stream>>>(bufA, esrc, row_ptr, dis,
                                                      b1, g1, be1, m1, v1, bufB, N_NODES);
    // ---- layer 2 ----
    gemm_nk128<<<gemm_blocks, 256, 0, stream>>>(bufB, W2, bufA, N_NODES);
    gather_bn_relu<<<gather_blocks, 256, 0, stream>>>(bufA, esrc, row_ptr, dis,
                                                      b2, g2, be2, m2, v2, bufB, N_NODES);
    // ---- pool + head ----
    pool_sum<<<(N_NODES + 31) / 32, 128, 0, stream>>>(bufB, batch, sums, N_NODES);
    final_lin<<<NGRAPH, 128, 0, stream>>>(sums, cnt, Wlin, blin, out);
}

// Round 3
// 417.804 us; speedup vs baseline: 3.7957x; 1.3347x over previous
//
#include <hip/hip_runtime.h>
#include <hip/hip_bf16.h>

#define N_NODES 50000
#define N_EDGES 800000
#define HDIM 128
#define NGRAPH 512
#define NCLS 10
#define BN_EPS 1e-5f
#define SCAN_B 256                      // elements per scan block
#define SCAN_NB ((N_NODES + SCAN_B - 1) / SCAN_B)   // 196

// ---------------------------------------------------------------------------
// deg_i[dst]++ (int) over edges; cnt[batch]++ (float) over nodes.
// ---------------------------------------------------------------------------
__global__ __launch_bounds__(256) void deg_count(const int* __restrict__ dst,
                                                 const int* __restrict__ batch,
                                                 int* __restrict__ deg_i,
                                                 float* __restrict__ cnt,
                                                 int ne, int n)
{
    int i = blockIdx.x * 256 + threadIdx.x;
    if (i < ne) atomicAdd(&deg_i[dst[i]], 1);
    if (i < n)  atomicAdd(&cnt[batch[i]], 1.0f);
}

// dis[i] = rsqrt(deg_i[i] + 1)   (+1 = self loop)
__global__ __launch_bounds__(256) void rsqrt_deg(const int* __restrict__ deg_i,
                                                 float* __restrict__ dis, int n)
{
    int i = blockIdx.x * 256 + threadIdx.x;
    if (i < n) dis[i] = rsqrtf((float)deg_i[i] + 1.0f);
}

// ---------------------------------------------------------------------------
// 3-phase parallel exclusive scan of deg_i -> row_ptr.
// ---------------------------------------------------------------------------
__global__ __launch_bounds__(SCAN_B) void scan_reduce(const int* __restrict__ deg,
                                                      int* __restrict__ bsum, int n)
{
    __shared__ int lds[SCAN_B];
    int t = threadIdx.x;
    int i = blockIdx.x * SCAN_B + t;
    lds[t] = (i < n) ? deg[i] : 0;
    __syncthreads();
    #pragma unroll
    for (int off = SCAN_B / 2; off > 0; off >>= 1) {
        if (t < off) lds[t] += lds[t + off];
        __syncthreads();
    }
    if (t == 0) bsum[blockIdx.x] = lds[0];
}

__global__ __launch_bounds__(SCAN_B) void scan_bsum(const int* __restrict__ bsum,
                                                    int* __restrict__ boff, int nb)
{
    __shared__ int lds[SCAN_B];
    int t = threadIdx.x;
    int v = (t < nb) ? bsum[t] : 0;
    lds[t] = v;
    __syncthreads();
    #pragma unroll
    for (int off = 1; off < SCAN_B; off <<= 1) {
        int u = (t >= off) ? lds[t - off] : 0;
        __syncthreads();
        lds[t] += u;
        __syncthreads();
    }
    if (t < nb) boff[t] = lds[t] - v;     // exclusive prefix of block sums
}

__global__ __launch_bounds__(SCAN_B) void scan_final(const int* __restrict__ deg,
                                                     const int* __restrict__ boff,
                                                     int* __restrict__ row_ptr, int n)
{
    __shared__ int lds[SCAN_B];
    int t = threadIdx.x;
    int i = blockIdx.x * SCAN_B + t;
    int v = (i < n) ? deg[i] : 0;
    lds[t] = v;
    __syncthreads();
    #pragma unroll
    for (int off = 1; off < SCAN_B; off <<= 1) {
        int u = (t >= off) ? lds[t - off] : 0;
        __syncthreads();
        lds[t] += u;
        __syncthreads();
    }
    int incl = lds[t] + boff[blockIdx.x];
    if (i < n)      row_ptr[i] = incl - v;
    if (i == n - 1) row_ptr[n] = incl;
}

// ---------------------------------------------------------------------------
// Scatter edges into dst-sorted order: esrc[row_ptr[d] + cursor[d]++] = src.
// ---------------------------------------------------------------------------
__global__ __launch_bounds__(256) void scatter_edges(const int* __restrict__ src,
                                                     const int* __restrict__ dst,
                                                     const int* __restrict__ row_ptr,
                                                     int* __restrict__ cursor,
                                                     int* __restrict__ esrc, int ne)
{
    int e = blockIdx.x * 256 + threadIdx.x;
    if (e >= ne) return;
    int d = dst[e];
    int pos = row_ptr[d] + atomicAdd(&cursor[d], 1);
    esrc[pos] = src[e];
}

// ---------------------------------------------------------------------------
// Y[n][0:128] = X[n][0:128] @ W[128][128], fp32 (no fp32 MFMA on CDNA4).
// ---------------------------------------------------------------------------
__global__ __launch_bounds__(256) void gemm_nk128(const float* __restrict__ X,
                                                  const float* __restrict__ W,
                                                  float* __restrict__ Y, int nrows)
{
    __shared__ float xs[32][36];
    __shared__ float ws[32][128];
    const int t   = threadIdx.x;
    const int row0 = blockIdx.x * 32;
    const int tx  = t & 31;
    const int ty  = t >> 5;

    float acc[4][4];
    #pragma unroll
    for (int i = 0; i < 4; ++i)
        #pragma unroll
        for (int j = 0; j < 4; ++j) acc[i][j] = 0.f;

    const int lr = t >> 3;
    const int lk = (t & 7) << 2;
    const int wr = t >> 5;
    const int wc = (t & 31) << 2;

    for (int k0 = 0; k0 < 128; k0 += 32) {
        float4 xv = make_float4(0.f, 0.f, 0.f, 0.f);
        int grow = row0 + lr;
        if (grow < nrows) xv = *(const float4*)(X + (size_t)grow * HDIM + k0 + lk);
        xs[lr][lk] = xv.x; xs[lr][lk + 1] = xv.y; xs[lr][lk + 2] = xv.z; xs[lr][lk + 3] = xv.w;
        #pragma unroll
        for (int i = 0; i < 4; ++i) {
            int kk = wr + i * 8;
            *(float4*)&ws[kk][wc] = *(const float4*)(W + (size_t)(k0 + kk) * HDIM + wc);
        }
        __syncthreads();
        #pragma unroll
        for (int kk = 0; kk < 32; kk += 4) {
            float4 wv[4];
            #pragma unroll
            for (int j = 0; j < 4; ++j) wv[j] = *(const float4*)&ws[kk + j][tx << 2];
            #pragma unroll
            for (int i = 0; i < 4; ++i) {
                float4 xr = *(const float4*)&xs[ty * 4 + i][kk];
                acc[i][0] += xr.x * wv[0].x; acc[i][1] += xr.x * wv[0].y;
                acc[i][2] += xr.x * wv[0].z; acc[i][3] += xr.x * wv[0].w;
                acc[i][0] += xr.y * wv[1].x; acc[i][1] += xr.y * wv[1].y;
                acc[i][2] += xr.y * wv[1].z; acc[i][3] += xr.y * wv[1].w;
                acc[i][0] += xr.z * wv[2].x; acc[i][1] += xr.z * wv[2].y;
                acc[i][2] += xr.z * wv[2].z; acc[i][3] += xr.z * wv[2].w;
                acc[i][0] += xr.w * wv[3].x; acc[i][1] += xr.w * wv[3].y;
                acc[i][2] += xr.w * wv[3].z; acc[i][3] += xr.w * wv[3].w;
            }
        }
        __syncthreads();
    }
    #pragma unroll
    for (int i = 0; i < 4; ++i) {
        int grow = row0 + ty * 4 + i;
        if (grow < nrows)
            *(float4*)(Y + (size_t)grow * HDIM + (tx << 2)) =
                make_float4(acc[i][0], acc[i][1], acc[i][2], acc[i][3]);
    }
}

// ---------------------------------------------------------------------------
// CSR gather + self-loop + bias + BN(eval) + ReLU, fused.
// One node per wave; each HALF-wave processes a different edge with float4
// loads (lane handles 4 channels), cross-half shfl_xor reduction at the end.
// ---------------------------------------------------------------------------
__global__ __launch_bounds__(256) void gather_bn_relu(const float* __restrict__ h,
                                                      const int* __restrict__ esrc,
                                                      const int* __restrict__ row_ptr,
                                                      const float* __restrict__ dis,
                                                      const float* __restrict__ b,
                                                      const float* __restrict__ gamma,
                                                      const float* __restrict__ beta,
                                                      const float* __restrict__ mean,
                                                      const float* __restrict__ var,
                                                      float* __restrict__ out, int n)
{
    int node = blockIdx.x * 4 + (threadIdx.x >> 6);
    if (node >= n) return;
    const int lane = threadIdx.x & 63;
    const int half = lane >> 5;          // 0 or 1: which edge of the pair
    const int c    = (lane & 31) << 2;   // 4 channels per lane
    const int e0 = row_ptr[node], e1 = row_ptr[node + 1];
    const float dd = dis[node];

    float ax = 0.f, ay = 0.f, az = 0.f, aw = 0.f;
    for (int e = e0 + half; e < e1; e += 2) {
        int s = esrc[e];
        float nm = dis[s] * dd;
        float4 v = *(const float4*)(h + (size_t)s * HDIM + c);
        ax += v.x * nm; ay += v.y * nm; az += v.z * nm; aw += v.w * nm;
    }
    // combine the two half-wave partials (lane i <-> lane i+32)
    ax += __shfl_xor(ax, 32);
    ay += __shfl_xor(ay, 32);
    az += __shfl_xor(az, 32);
    aw += __shfl_xor(aw, 32);

    if (half == 0) {
        float4 hv = *(const float4*)(h + (size_t)node * HDIM + c);
        float a[4] = {ax + hv.x * dd * dd, ay + hv.y * dd * dd,
                      az + hv.z * dd * dd, aw + hv.w * dd * dd};
        float o[4];
        #pragma unroll
        for (int j = 0; j < 4; ++j) {
            float sc = gamma[c + j] * rsqrtf(var[c + j] + BN_EPS);
            float r  = (a[j] + b[c + j] - mean[c + j]) * sc + beta[c + j];
            o[j] = fmaxf(r, 0.f);
        }
        *(float4*)(out + (size_t)node * HDIM + c) = make_float4(o[0], o[1], o[2], o[3]);
    }
}

// ---------------------------------------------------------------------------
// Pool: sums[batch[n]][c] += h[n][c]; batch sorted -> segment-local acc.
// ---------------------------------------------------------------------------
__global__ __launch_bounds__(128) void pool_sum(const float* __restrict__ h,
                                                const int* __restrict__ batch,
                                                float* __restrict__ sums, int n)
{
    int c  = threadIdx.x;
    int n0 = blockIdx.x * 32;
    if (n0 >= n) return;
    int nend = min(n0 + 32, n);
    int curg = batch[n0];
    float acc = 0.f;
    for (int i = n0; i < nend; ++i) {
        int g   = batch[i];
        float v = h[(size_t)i * HDIM + c];
        if (g != curg) {
            atomicAdd(&sums[(size_t)curg * HDIM + c], acc);
            acc = 0.f; curg = g;
        }
        acc += v;
    }
    atomicAdd(&sums[(size_t)curg * HDIM + c], acc);
}

// ---------------------------------------------------------------------------
// out[g][c] = (sums[g]/max(cnt[g],1)) . Wlin[:,c] + blin[c]
// ---------------------------------------------------------------------------
__global__ __launch_bounds__(128) void final_lin(const float* __restrict__ sums,
                                                 const float* __restrict__ cnt,
                                                 const float* __restrict__ Wlin,
                                                 const float* __restrict__ blin,
                                                 float* __restrict__ out)
{
    __shared__ float red[NCLS][2];
    int g = blockIdx.x;
    int t = threadIdx.x;
    float ic = 1.f / fmaxf(cnt[g], 1.f);
    float v  = sums[(size_t)g * HDIM + t] * ic;
    float p[NCLS];
    #pragma unroll
    for (int c = 0; c < NCLS; ++c) p[c] = v * Wlin[t * NCLS + c];
    #pragma unroll
    for (int c = 0; c < NCLS; ++c) {
        float x = p[c];
        for (int off = 32; off > 0; off >>= 1) x += __shfl_down(x, off);
        if ((t & 63) == 0) red[c][t >> 6] = x;
    }
    __syncthreads();
    if (t < NCLS) out[g * NCLS + t] = red[t][0] + red[t][1] + blin[t];
}

// ---------------------------------------------------------------------------
extern "C" void kernel_launch(void* const* d_in, const int* in_sizes, int n_in,
                              void* d_out, int out_size, void* d_ws, size_t ws_size,
                              hipStream_t stream)
{
    const float* x     = (const float*)d_in[0];
    const int*   ei    = (const int*)d_in[1];
    const int*   srcp  = ei;
    const int*   dstp  = ei + N_EDGES;
    const int*   batch = (const int*)d_in[2];
    const float* W1    = (const float*)d_in[3];
    const float* b1    = (const float*)d_in[4];
    const float* g1    = (const float*)d_in[5];
    const float* be1   = (const float*)d_in[6];
    const float* m1    = (const float*)d_in[7];
    const float* v1    = (const float*)d_in[8];
    const float* W2    = (const float*)d_in[9];
    const float* b2    = (const float*)d_in[10];
    const float* g2    = (const float*)d_in[11];
    const float* be2   = (const float*)d_in[12];
    const float* m2    = (const float*)d_in[13];
    const float* v2    = (const float*)d_in[14];
    const float* Wlin  = (const float*)d_in[15];
    const float* blin  = (const float*)d_in[16];
    float*       out   = (float*)d_out;

    // workspace layout:
    // bufA | bufB | esrc | row_ptr | dis | deg_i | cnt | sums | bsum | boff
    float* bufA    = (float*)d_ws;
    float* bufB    = bufA + (size_t)N_NODES * HDIM;
    int*   esrc    = (int*)(bufB + (size_t)N_NODES * HDIM);
    int*   row_ptr = esrc + N_EDGES;
    float* dis     = (float*)(row_ptr + N_NODES + 1);
    int*   deg_i   = (int*)(dis + N_NODES);
    float* cnt     = (float*)(deg_i + N_NODES);
    float* sums    = cnt + NGRAPH;
    int*   bsum    = (int*)(sums + (size_t)NGRAPH * HDIM);
    int*   boff    = bsum + SCAN_NB;

    // zero deg_i | cnt | sums in one contiguous memset
    hipMemsetAsync(deg_i, 0,
                   (N_NODES + NGRAPH + (size_t)NGRAPH * HDIM) * sizeof(float), stream);

    // ---- CSR build ----
    deg_count<<<(N_EDGES + 255) / 256, 256, 0, stream>>>(dstp, batch, deg_i, cnt,
                                                         N_EDGES, N_NODES);
    rsqrt_deg<<<(N_NODES + 255) / 256, 256, 0, stream>>>(deg_i, dis, N_NODES);
    scan_reduce<<<SCAN_NB, SCAN_B, 0, stream>>>(deg_i, bsum, N_NODES);
    scan_bsum<<<1, SCAN_B, 0, stream>>>(bsum, boff, SCAN_NB);
    scan_final<<<SCAN_NB, SCAN_B, 0, stream>>>(deg_i, boff, row_ptr, N_NODES);
    hipMemsetAsync(deg_i, 0, N_NODES * sizeof(int), stream);   // reuse as cursor
    scatter_edges<<<(N_EDGES + 255) / 256, 256, 0, stream>>>(srcp, dstp, row_ptr,
                                                             deg_i, esrc, N_EDGES);

    const int gemm_blocks   = (N_NODES + 31) / 32;
    const int gather_blocks = (N_NODES + 3) / 4;

    // ---- layer 1 ----
    gemm_nk128<<<gemm_blocks, 256, 0, stream>>>(x, W1, bufA, N_NODES);
    gather_bn_relu<<<gather_blocks, 256, 0, stream>>>(bufA, esrc, row_ptr, dis,
                                                      b1, g1, be1, m1, v1, bufB, N_NODES);
    // ---- layer 2 ----
    gemm_nk128<<<gemm_blocks, 256, 0, stream>>>(bufB, W2, bufA, N_NODES);
    gather_bn_relu<<<gather_blocks, 256, 0, stream>>>(bufA, esrc, row_ptr, dis,
                                                      b2, g2, be2, m2, v2, bufB, N_NODES);
    // ---- pool + head ----
    pool_sum<<<(N_NODES + 31) / 32, 128, 0, stream>>>(bufB, batch, sums, N_NODES);
    final_lin<<<NGRAPH, 128, 0, stream>>>(sums, cnt, Wlin, blin, out);
}

// Round 4
// 336.707 us; speedup vs baseline: 4.7099x; 1.2409x over previous
//
#include <hip/hip_runtime.h>
#include <hip/hip_bf16.h>

#define N_NODES 50000
#define N_EDGES 800000
#define HDIM 128
#define NGRAPH 512
#define NCLS 10
#define BN_EPS 1e-5f
#define MAXDEG 64   // in-deg ~ Poisson(16) over 50k bins; P(any>=64) ~ 1e-14

// ---------------------------------------------------------------------------
// One-pass padded-bucket CSR build:
//   pos = deg[d]++  (memory-side atomic);  epad[d*MAXDEG + pos] = src
// Degrees and dst-grouped adjacency in a single 800k-atomic pass.
// ---------------------------------------------------------------------------
__global__ __launch_bounds__(256) void bucket_edges(const int* __restrict__ src,
                                                    const int* __restrict__ dst,
                                                    int* __restrict__ deg,
                                                    int* __restrict__ epad, int ne)
{
    int e = blockIdx.x * 256 + threadIdx.x;
    if (e >= ne) return;
    int d   = dst[e];
    int pos = atomicAdd(&deg[d], 1);
    epad[(size_t)d * MAXDEG + pos] = src[e];
}

// dis[i] = rsqrt(deg[i] + 1)   (+1 = self loop)
__global__ __launch_bounds__(256) void rsqrt_deg(const int* __restrict__ deg,
                                                 float* __restrict__ dis, int n)
{
    int i = blockIdx.x * 256 + threadIdx.x;
    if (i < n) dis[i] = rsqrtf((float)deg[i] + 1.0f);
}

// ---------------------------------------------------------------------------
// Y[n][0:128] = X[n][0:128] @ W[128][128], fp32 (no fp32 MFMA on CDNA4).
// 32 rows/block, 256 threads, 4x4 register tile, W+X staged in LDS.
// ---------------------------------------------------------------------------
__global__ __launch_bounds__(256) void gemm_nk128(const float* __restrict__ X,
                                                  const float* __restrict__ W,
                                                  float* __restrict__ Y, int nrows)
{
    __shared__ float xs[32][36];
    __shared__ float ws[32][128];
    const int t   = threadIdx.x;
    const int row0 = blockIdx.x * 32;
    const int tx  = t & 31;
    const int ty  = t >> 5;

    float acc[4][4];
    #pragma unroll
    for (int i = 0; i < 4; ++i)
        #pragma unroll
        for (int j = 0; j < 4; ++j) acc[i][j] = 0.f;

    const int lr = t >> 3;
    const int lk = (t & 7) << 2;
    const int wr = t >> 5;
    const int wc = (t & 31) << 2;

    for (int k0 = 0; k0 < 128; k0 += 32) {
        float4 xv = make_float4(0.f, 0.f, 0.f, 0.f);
        int grow = row0 + lr;
        if (grow < nrows) xv = *(const float4*)(X + (size_t)grow * HDIM + k0 + lk);
        xs[lr][lk] = xv.x; xs[lr][lk + 1] = xv.y; xs[lr][lk + 2] = xv.z; xs[lr][lk + 3] = xv.w;
        #pragma unroll
        for (int i = 0; i < 4; ++i) {
            int kk = wr + i * 8;
            *(float4*)&ws[kk][wc] = *(const float4*)(W + (size_t)(k0 + kk) * HDIM + wc);
        }
        __syncthreads();
        #pragma unroll
        for (int kk = 0; kk < 32; kk += 4) {
            float4 wv[4];
            #pragma unroll
            for (int j = 0; j < 4; ++j) wv[j] = *(const float4*)&ws[kk + j][tx << 2];
            #pragma unroll
            for (int i = 0; i < 4; ++i) {
                float4 xr = *(const float4*)&xs[ty * 4 + i][kk];
                acc[i][0] += xr.x * wv[0].x; acc[i][1] += xr.x * wv[0].y;
                acc[i][2] += xr.x * wv[0].z; acc[i][3] += xr.x * wv[0].w;
                acc[i][0] += xr.y * wv[1].x; acc[i][1] += xr.y * wv[1].y;
                acc[i][2] += xr.y * wv[1].z; acc[i][3] += xr.y * wv[1].w;
                acc[i][0] += xr.z * wv[2].x; acc[i][1] += xr.z * wv[2].y;
                acc[i][2] += xr.z * wv[2].z; acc[i][3] += xr.z * wv[2].w;
                acc[i][0] += xr.w * wv[3].x; acc[i][1] += xr.w * wv[3].y;
                acc[i][2] += xr.w * wv[3].z; acc[i][3] += xr.w * wv[3].w;
            }
        }
        __syncthreads();
    }
    #pragma unroll
    for (int i = 0; i < 4; ++i) {
        int grow = row0 + ty * 4 + i;
        if (grow < nrows)
            *(float4*)(Y + (size_t)grow * HDIM + (tx << 2)) =
                make_float4(acc[i][0], acc[i][1], acc[i][2], acc[i][3]);
    }
}

// ---------------------------------------------------------------------------
// Padded-bucket gather + self-loop + bias + BN(eval) + ReLU, fused.
// One node per wave; each HALF-wave processes a different edge with float4
// loads (lane handles 4 channels), cross-half shfl_xor reduction at the end.
// ---------------------------------------------------------------------------
__global__ __launch_bounds__(256) void gather_bn_relu(const float* __restrict__ h,
                                                      const int* __restrict__ epad,
                                                      const int* __restrict__ deg,
                                                      const float* __restrict__ dis,
                                                      const float* __restrict__ b,
                                                      const float* __restrict__ gamma,
                                                      const float* __restrict__ beta,
                                                      const float* __restrict__ mean,
                                                      const float* __restrict__ var,
                                                      float* __restrict__ out, int n)
{
    int node = blockIdx.x * 4 + (threadIdx.x >> 6);
    if (node >= n) return;
    const int lane = threadIdx.x & 63;
    const int half = lane >> 5;          // 0 or 1: which edge of the pair
    const int c    = (lane & 31) << 2;   // 4 channels per lane
    const int cnt_e = deg[node];
    const int base  = node * MAXDEG;
    const float dd  = dis[node];

    float ax = 0.f, ay = 0.f, az = 0.f, aw = 0.f;
    for (int j = half; j < cnt_e; j += 2) {
        int s = epad[base + j];
        float nm = dis[s] * dd;
        float4 v = *(const float4*)(h + (size_t)s * HDIM + c);
        ax += v.x * nm; ay += v.y * nm; az += v.z * nm; aw += v.w * nm;
    }
    // combine the two half-wave partials (lane i <-> lane i+32)
    ax += __shfl_xor(ax, 32);
    ay += __shfl_xor(ay, 32);
    az += __shfl_xor(az, 32);
    aw += __shfl_xor(aw, 32);

    if (half == 0) {
        float4 hv = *(const float4*)(h + (size_t)node * HDIM + c);
        float a[4] = {ax + hv.x * dd * dd, ay + hv.y * dd * dd,
                      az + hv.z * dd * dd, aw + hv.w * dd * dd};
        float o[4];
        #pragma unroll
        for (int j = 0; j < 4; ++j) {
            float sc = gamma[c + j] * rsqrtf(var[c + j] + BN_EPS);
            float r  = (a[j] + b[c + j] - mean[c + j]) * sc + beta[c + j];
            o[j] = fmaxf(r, 0.f);
        }
        *(float4*)(out + (size_t)node * HDIM + c) = make_float4(o[0], o[1], o[2], o[3]);
    }
}

// ---------------------------------------------------------------------------
// Pool: sums[batch[n]][c] += h[n][c]; batch sorted -> segment-local acc.
// Also accumulates per-graph node counts (thread 0 of each block).
// ---------------------------------------------------------------------------
__global__ __launch_bounds__(128) void pool_sum(const float* __restrict__ h,
                                                const int* __restrict__ batch,
                                                float* __restrict__ sums,
                                                float* __restrict__ cnt, int n)
{
    int c  = threadIdx.x;
    int n0 = blockIdx.x * 32;
    if (n0 >= n) return;
    int nend = min(n0 + 32, n);
    int curg = batch[n0];
    float acc = 0.f;
    int run = 0;
    for (int i = n0; i < nend; ++i) {
        int g   = batch[i];                      // uniform across block
        float v = h[(size_t)i * HDIM + c];
        if (g != curg) {
            atomicAdd(&sums[(size_t)curg * HDIM + c], acc);
            if (c == 0) atomicAdd(&cnt[curg], (float)run);
            acc = 0.f; run = 0; curg = g;
        }
        acc += v; run++;
    }
    atomicAdd(&sums[(size_t)curg * HDIM + c], acc);
    if (c == 0) atomicAdd(&cnt[curg], (float)run);
}

// ---------------------------------------------------------------------------
// out[g][c] = (sums[g]/max(cnt[g],1)) . Wlin[:,c] + blin[c]
// ---------------------------------------------------------------------------
__global__ __launch_bounds__(128) void final_lin(const float* __restrict__ sums,
                                                 const float* __restrict__ cnt,
                                                 const float* __restrict__ Wlin,
                                                 const float* __restrict__ blin,
                                                 float* __restrict__ out)
{
    __shared__ float red[NCLS][2];
    int g = blockIdx.x;
    int t = threadIdx.x;
    float ic = 1.f / fmaxf(cnt[g], 1.f);
    float v  = sums[(size_t)g * HDIM + t] * ic;
    float p[NCLS];
    #pragma unroll
    for (int c = 0; c < NCLS; ++c) p[c] = v * Wlin[t * NCLS + c];
    #pragma unroll
    for (int c = 0; c < NCLS; ++c) {
        float x = p[c];
        for (int off = 32; off > 0; off >>= 1) x += __shfl_down(x, off);
        if ((t & 63) == 0) red[c][t >> 6] = x;
    }
    __syncthreads();
    if (t < NCLS) out[g * NCLS + t] = red[t][0] + red[t][1] + blin[t];
}

// ---------------------------------------------------------------------------
extern "C" void kernel_launch(void* const* d_in, const int* in_sizes, int n_in,
                              void* d_out, int out_size, void* d_ws, size_t ws_size,
                              hipStream_t stream)
{
    const float* x     = (const float*)d_in[0];
    const int*   ei    = (const int*)d_in[1];
    const int*   srcp  = ei;
    const int*   dstp  = ei + N_EDGES;
    const int*   batch = (const int*)d_in[2];
    const float* W1    = (const float*)d_in[3];
    const float* b1    = (const float*)d_in[4];
    const float* g1    = (const float*)d_in[5];
    const float* be1   = (const float*)d_in[6];
    const float* m1    = (const float*)d_in[7];
    const float* v1    = (const float*)d_in[8];
    const float* W2    = (const float*)d_in[9];
    const float* b2    = (const float*)d_in[10];
    const float* g2    = (const float*)d_in[11];
    const float* be2   = (const float*)d_in[12];
    const float* m2    = (const float*)d_in[13];
    const float* v2    = (const float*)d_in[14];
    const float* Wlin  = (const float*)d_in[15];
    const float* blin  = (const float*)d_in[16];
    float*       out   = (float*)d_out;

    // workspace layout (~64.8 MiB):
    // bufA | bufB | epad | deg | cnt | sums | dis
    float* bufA = (float*)d_ws;
    float* bufB = bufA + (size_t)N_NODES * HDIM;
    int*   epad = (int*)(bufB + (size_t)N_NODES * HDIM);
    int*   deg  = epad + (size_t)N_NODES * MAXDEG;
    float* cnt  = (float*)(deg + N_NODES);
    float* sums = cnt + NGRAPH;
    float* dis  = sums + (size_t)NGRAPH * HDIM;

    // zero deg | cnt | sums in one contiguous memset
    hipMemsetAsync(deg, 0,
                   (N_NODES + NGRAPH + (size_t)NGRAPH * HDIM) * sizeof(float), stream);

    // ---- one-pass CSR (padded buckets) ----
    bucket_edges<<<(N_EDGES + 255) / 256, 256, 0, stream>>>(srcp, dstp, deg, epad, N_EDGES);
    rsqrt_deg<<<(N_NODES + 255) / 256, 256, 0, stream>>>(deg, dis, N_NODES);

    const int gemm_blocks   = (N_NODES + 31) / 32;
    const int gather_blocks = (N_NODES + 3) / 4;

    // ---- layer 1 ----
    gemm_nk128<<<gemm_blocks, 256, 0, stream>>>(x, W1, bufA, N_NODES);
    gather_bn_relu<<<gather_blocks, 256, 0, stream>>>(bufA, epad, deg, dis,
                                                      b1, g1, be1, m1, v1, bufB, N_NODES);
    // ---- layer 2 ----
    gemm_nk128<<<gemm_blocks, 256, 0, stream>>>(bufB, W2, bufA, N_NODES);
    gather_bn_relu<<<gather_blocks, 256, 0, stream>>>(bufA, epad, deg, dis,
                                                      b2, g2, be2, m2, v2, bufB, N_NODES);
    // ---- pool + head ----
    pool_sum<<<(N_NODES + 31) / 32, 128, 0, stream>>>(bufB, batch, sums, cnt, N_NODES);
    final_lin<<<NGRAPH, 128, 0, stream>>>(sums, cnt, Wlin, blin, out);
}

// Round 5
// 300.683 us; speedup vs baseline: 5.2742x; 1.1198x over previous
//
#include <hip/hip_runtime.h>
#include <hip/hip_bf16.h>

#define N_NODES 50000
#define N_EDGES 800000
#define HDIM 128
#define NGRAPH 512
#define NCLS 10
#define BN_EPS 1e-5f
#define MAXDEG 64   // in-deg ~ Poisson(16) over 50k bins; P(any>=64) ~ 1e-14

typedef unsigned int  uint32;
typedef unsigned short ushort16;

// bf16x2 (packed in a uint) -> float2
__device__ inline float2 bf2f(uint32 u) {
    return make_float2(__uint_as_float(u << 16), __uint_as_float(u & 0xffff0000u));
}
// fp32 -> bf16 bits, round-to-nearest-even
__device__ inline ushort16 f2bf(float f) {
    uint32 u = __float_as_uint(f);
    u += 0x7fffu + ((u >> 16) & 1u);
    return (ushort16)(u >> 16);
}
__device__ inline uint32 packbf2(float lo, float hi) {
    return (uint32)f2bf(lo) | ((uint32)f2bf(hi) << 16);
}

// ---------------------------------------------------------------------------
// One-pass padded-bucket CSR build:
//   pos = deg[d]++  (memory-side atomic);  epad[d*MAXDEG + pos] = src
// ---------------------------------------------------------------------------
__global__ __launch_bounds__(256) void bucket_edges(const int* __restrict__ src,
                                                    const int* __restrict__ dst,
                                                    int* __restrict__ deg,
                                                    int* __restrict__ epad, int ne)
{
    int e = blockIdx.x * 256 + threadIdx.x;
    if (e >= ne) return;
    int d   = dst[e];
    int pos = atomicAdd(&deg[d], 1);
    epad[(size_t)d * MAXDEG + pos] = src[e];
}

// dis[i] = rsqrt(deg[i] + 1)   (+1 = self loop)
__global__ __launch_bounds__(256) void rsqrt_deg(const int* __restrict__ deg,
                                                 float* __restrict__ dis, int n)
{
    int i = blockIdx.x * 256 + threadIdx.x;
    if (i < n) dis[i] = rsqrtf((float)deg[i] + 1.0f);
}

// ---------------------------------------------------------------------------
// Y[n][0:128](bf16) = X[n][0:128] @ W[128][128], fp32 VALU compute.
// Templated input dtype: float (layer 1) or bf16-as-ushort (layer 2).
// 32 rows/block, 256 threads, 4x4 register tile, W+X staged in LDS (fp32).
// ---------------------------------------------------------------------------
template <typename TIN>
__global__ __launch_bounds__(256) void gemm_nk128(const TIN* __restrict__ X,
                                                  const float* __restrict__ W,
                                                  ushort16* __restrict__ Y, int nrows)
{
    __shared__ float xs[32][36];
    __shared__ float ws[32][128];
    const int t    = threadIdx.x;
    const int row0 = blockIdx.x * 32;
    const int tx   = t & 31;
    const int ty   = t >> 5;

    float acc[4][4];
    #pragma unroll
    for (int i = 0; i < 4; ++i)
        #pragma unroll
        for (int j = 0; j < 4; ++j) acc[i][j] = 0.f;

    const int lr = t >> 3;          // x-stage row 0..31
    const int lk = (t & 7) << 2;    // x-stage k offset (4 floats)
    const int wr = t >> 5;
    const int wc = (t & 31) << 2;

    for (int k0 = 0; k0 < 128; k0 += 32) {
        float4 xv = make_float4(0.f, 0.f, 0.f, 0.f);
        int grow = row0 + lr;
        if (grow < nrows) {
            const TIN* p = X + (size_t)grow * HDIM + k0 + lk;
            if constexpr (sizeof(TIN) == 4) {
                xv = *(const float4*)p;
            } else {
                uint2 u = *(const uint2*)p;       // 4 bf16
                float2 a = bf2f(u.x), bb = bf2f(u.y);
                xv = make_float4(a.x, a.y, bb.x, bb.y);
            }
        }
        xs[lr][lk] = xv.x; xs[lr][lk + 1] = xv.y; xs[lr][lk + 2] = xv.z; xs[lr][lk + 3] = xv.w;
        #pragma unroll
        for (int i = 0; i < 4; ++i) {
            int kk = wr + i * 8;
            *(float4*)&ws[kk][wc] = *(const float4*)(W + (size_t)(k0 + kk) * HDIM + wc);
        }
        __syncthreads();
        #pragma unroll
        for (int kk = 0; kk < 32; kk += 4) {
            float4 wv[4];
            #pragma unroll
            for (int j = 0; j < 4; ++j) wv[j] = *(const float4*)&ws[kk + j][tx << 2];
            #pragma unroll
            for (int i = 0; i < 4; ++i) {
                float4 xr = *(const float4*)&xs[ty * 4 + i][kk];
                acc[i][0] += xr.x * wv[0].x; acc[i][1] += xr.x * wv[0].y;
                acc[i][2] += xr.x * wv[0].z; acc[i][3] += xr.x * wv[0].w;
                acc[i][0] += xr.y * wv[1].x; acc[i][1] += xr.y * wv[1].y;
                acc[i][2] += xr.y * wv[1].z; acc[i][3] += xr.y * wv[1].w;
                acc[i][0] += xr.z * wv[2].x; acc[i][1] += xr.z * wv[2].y;
                acc[i][2] += xr.z * wv[2].z; acc[i][3] += xr.z * wv[2].w;
                acc[i][0] += xr.w * wv[3].x; acc[i][1] += xr.w * wv[3].y;
                acc[i][2] += xr.w * wv[3].z; acc[i][3] += xr.w * wv[3].w;
            }
        }
        __syncthreads();
    }
    #pragma unroll
    for (int i = 0; i < 4; ++i) {
        int grow = row0 + ty * 4 + i;
        if (grow < nrows) {
            uint2 o;
            o.x = packbf2(acc[i][0], acc[i][1]);
            o.y = packbf2(acc[i][2], acc[i][3]);
            *(uint2*)(Y + (size_t)grow * HDIM + (tx << 2)) = o;
        }
    }
}

// ---------------------------------------------------------------------------
// Padded-bucket gather + self-loop + bias + BN(eval) + ReLU, fused. bf16 h.
// One node per wave; QUARTER-wave (16 lanes) per edge, lane loads 8 channels
// (16B dwordx4). Edge ids & norms preloaded per-lane, distributed by shfl.
// 4 edges in flight per iteration; cross-quarter shfl_xor reduction.
// ---------------------------------------------------------------------------
__global__ __launch_bounds__(256) void gather_bn_relu(const ushort16* __restrict__ h,
                                                      const int* __restrict__ epad,
                                                      const int* __restrict__ deg,
                                                      const float* __restrict__ dis,
                                                      const float* __restrict__ b,
                                                      const float* __restrict__ gamma,
                                                      const float* __restrict__ beta,
                                                      const float* __restrict__ mean,
                                                      const float* __restrict__ var,
                                                      ushort16* __restrict__ out, int n)
{
    int node = blockIdx.x * 4 + (threadIdx.x >> 6);
    if (node >= n) return;
    const int lane = threadIdx.x & 63;
    const int q    = lane >> 4;          // quarter 0..3: which edge of the 4
    const int ci   = (lane & 15) << 3;   // 8 channels per lane
    const int cnt_e = deg[node];
    const int base  = node * MAXDEG;
    const float dd  = dis[node];

    // preload this node's edge list: lane l owns edge l (cnt_e <= 64)
    int   s_all  = 0;
    float nm_all = 0.f;
    if (lane < cnt_e) {
        s_all  = epad[base + lane];
        nm_all = dis[s_all] * dd;
    }

    float acc[8] = {0.f, 0.f, 0.f, 0.f, 0.f, 0.f, 0.f, 0.f};
    for (int j = q; j < cnt_e; j += 4) {
        int   s  = __shfl(s_all, j);
        float nm = __shfl(nm_all, j);
        uint4 v  = *(const uint4*)(h + (size_t)s * HDIM + ci);
        float2 f0 = bf2f(v.x), f1 = bf2f(v.y), f2 = bf2f(v.z), f3 = bf2f(v.w);
        acc[0] += f0.x * nm; acc[1] += f0.y * nm;
        acc[2] += f1.x * nm; acc[3] += f1.y * nm;
        acc[4] += f2.x * nm; acc[5] += f2.y * nm;
        acc[6] += f3.x * nm; acc[7] += f3.y * nm;
    }
    #pragma unroll
    for (int k = 0; k < 8; ++k) {
        acc[k] += __shfl_xor(acc[k], 16);
        acc[k] += __shfl_xor(acc[k], 32);
    }

    if (q == 0) {
        uint4 hv = *(const uint4*)(h + (size_t)node * HDIM + ci);
        float2 g0 = bf2f(hv.x), g1 = bf2f(hv.y), g2 = bf2f(hv.z), g3 = bf2f(hv.w);
        float dd2 = dd * dd;
        float a[8] = {acc[0] + g0.x * dd2, acc[1] + g0.y * dd2,
                      acc[2] + g1.x * dd2, acc[3] + g1.y * dd2,
                      acc[4] + g2.x * dd2, acc[5] + g2.y * dd2,
                      acc[6] + g3.x * dd2, acc[7] + g3.y * dd2};
        float o[8];
        #pragma unroll
        for (int k = 0; k < 8; ++k) {
            int c = ci + k;
            float sc = gamma[c] * rsqrtf(var[c] + BN_EPS);
            float r  = (a[k] + b[c] - mean[c]) * sc + beta[c];
            o[k] = fmaxf(r, 0.f);
        }
        uint4 ov;
        ov.x = packbf2(o[0], o[1]); ov.y = packbf2(o[2], o[3]);
        ov.z = packbf2(o[4], o[5]); ov.w = packbf2(o[6], o[7]);
        *(uint4*)(out + (size_t)node * HDIM + ci) = ov;
    }
}

// ---------------------------------------------------------------------------
// Pool: sums[batch[n]][c] += h[n][c] (bf16 h, fp32 sums); batch sorted.
// Also accumulates per-graph node counts (thread 0 of each block).
// ---------------------------------------------------------------------------
__global__ __launch_bounds__(128) void pool_sum(const ushort16* __restrict__ h,
                                                const int* __restrict__ batch,
                                                float* __restrict__ sums,
                                                float* __restrict__ cnt, int n)
{
    int c  = threadIdx.x;
    int n0 = blockIdx.x * 32;
    if (n0 >= n) return;
    int nend = min(n0 + 32, n);
    int curg = batch[n0];
    float acc = 0.f;
    int run = 0;
    for (int i = n0; i < nend; ++i) {
        int g   = batch[i];
        float v = __uint_as_float((uint32)h[(size_t)i * HDIM + c] << 16);
        if (g != curg) {
            atomicAdd(&sums[(size_t)curg * HDIM + c], acc);
            if (c == 0) atomicAdd(&cnt[curg], (float)run);
            acc = 0.f; run = 0; curg = g;
        }
        acc += v; run++;
    }
    atomicAdd(&sums[(size_t)curg * HDIM + c], acc);
    if (c == 0) atomicAdd(&cnt[curg], (float)run);
}

// ---------------------------------------------------------------------------
// out[g][c] = (sums[g]/max(cnt[g],1)) . Wlin[:,c] + blin[c]
// ---------------------------------------------------------------------------
__global__ __launch_bounds__(128) void final_lin(const float* __restrict__ sums,
                                                 const float* __restrict__ cnt,
                                                 const float* __restrict__ Wlin,
                                                 const float* __restrict__ blin,
                                                 float* __restrict__ out)
{
    __shared__ float red[NCLS][2];
    int g = blockIdx.x;
    int t = threadIdx.x;
    float ic = 1.f / fmaxf(cnt[g], 1.f);
    float v  = sums[(size_t)g * HDIM + t] * ic;
    float p[NCLS];
    #pragma unroll
    for (int c = 0; c < NCLS; ++c) p[c] = v * Wlin[t * NCLS + c];
    #pragma unroll
    for (int c = 0; c < NCLS; ++c) {
        float x = p[c];
        for (int off = 32; off > 0; off >>= 1) x += __shfl_down(x, off);
        if ((t & 63) == 0) red[c][t >> 6] = x;
    }
    __syncthreads();
    if (t < NCLS) out[g * NCLS + t] = red[t][0] + red[t][1] + blin[t];
}

// ---------------------------------------------------------------------------
extern "C" void kernel_launch(void* const* d_in, const int* in_sizes, int n_in,
                              void* d_out, int out_size, void* d_ws, size_t ws_size,
                              hipStream_t stream)
{
    const float* x     = (const float*)d_in[0];
    const int*   ei    = (const int*)d_in[1];
    const int*   srcp  = ei;
    const int*   dstp  = ei + N_EDGES;
    const int*   batch = (const int*)d_in[2];
    const float* W1    = (const float*)d_in[3];
    const float* b1    = (const float*)d_in[4];
    const float* g1    = (const float*)d_in[5];
    const float* be1   = (const float*)d_in[6];
    const float* m1    = (const float*)d_in[7];
    const float* v1    = (const float*)d_in[8];
    const float* W2    = (const float*)d_in[9];
    const float* b2    = (const float*)d_in[10];
    const float* g2    = (const float*)d_in[11];
    const float* be2   = (const float*)d_in[12];
    const float* m2    = (const float*)d_in[13];
    const float* v2    = (const float*)d_in[14];
    const float* Wlin  = (const float*)d_in[15];
    const float* blin  = (const float*)d_in[16];
    float*       out   = (float*)d_out;

    // workspace layout (~40 MiB):
    // bufA(bf16) | bufB(bf16) | epad | deg | cnt | sums | dis
    ushort16* bufA = (ushort16*)d_ws;
    ushort16* bufB = bufA + (size_t)N_NODES * HDIM;
    int*   epad = (int*)(bufB + (size_t)N_NODES * HDIM);
    int*   deg  = epad + (size_t)N_NODES * MAXDEG;
    float* cnt  = (float*)(deg + N_NODES);
    float* sums = cnt + NGRAPH;
    float* dis  = sums + (size_t)NGRAPH * HDIM;

    // zero deg | cnt | sums in one contiguous memset
    hipMemsetAsync(deg, 0,
                   (N_NODES + NGRAPH + (size_t)NGRAPH * HDIM) * sizeof(float), stream);

    // ---- one-pass CSR (padded buckets) ----
    bucket_edges<<<(N_EDGES + 255) / 256, 256, 0, stream>>>(srcp, dstp, deg, epad, N_EDGES);
    rsqrt_deg<<<(N_NODES + 255) / 256, 256, 0, stream>>>(deg, dis, N_NODES);

    const int gemm_blocks   = (N_NODES + 31) / 32;
    const int gather_blocks = (N_NODES + 3) / 4;

    // ---- layer 1 ----
    gemm_nk128<float><<<gemm_blocks, 256, 0, stream>>>(x, W1, bufA, N_NODES);
    gather_bn_relu<<<gather_blocks, 256, 0, stream>>>(bufA, epad, deg, dis,
                                                      b1, g1, be1, m1, v1, bufB, N_NODES);
    // ---- layer 2 ----
    gemm_nk128<ushort16><<<gemm_blocks, 256, 0, stream>>>(bufB, W2, bufA, N_NODES);
    gather_bn_relu<<<gather_blocks, 256, 0, stream>>>(bufA, epad, deg, dis,
                                                      b2, g2, be2, m2, v2, bufB, N_NODES);
    // ---- pool + head ----
    pool_sum<<<(N_NODES + 31) / 32, 128, 0, stream>>>(bufB, batch, sums, cnt, N_NODES);
    final_lin<<<NGRAPH, 128, 0, stream>>>(sums, cnt, Wlin, blin, out);
}

// Round 7
// 257.256 us; speedup vs baseline: 6.1645x; 1.1688x over previous
//
#include <hip/hip_runtime.h>
#include <hip/hip_bf16.h>
#include <hip/hip_fp16.h>

#define N_NODES 50000
#define N_EDGES 800000
#define HDIM 128
#define NGRAPH 512
#define NCLS 10
#define BN_EPS 1e-5f
#define MAXDEG 64   // in-deg ~ Poisson(16) over 50k bins; P(any>=64) ~ 1e-14

typedef unsigned int   uint32;
typedef unsigned short u16;
typedef __attribute__((ext_vector_type(8))) _Float16 half8;  // 8 fp16 (4 VGPRs)
typedef __attribute__((ext_vector_type(4))) float f32x4;

// fp32 -> fp16 bits (round-to-nearest-even)
__device__ inline u16 f2h(float f) {
    return __half_as_ushort(__float2half(f));
}
// fp16x2 (packed in a uint) -> float2
__device__ inline float2 h2f2(uint32 u) {
    __half2 h = *(__half2*)&u;
    return __half22float2(h);
}
__device__ inline uint32 packh2(float lo, float hi) {
    return (uint32)f2h(lo) | ((uint32)f2h(hi) << 16);
}

#define GEMM1_BLOCKS 1563                  // ceil(50000/32)
#define W2T_BLOCKS 8
#define FRONT_GRID (W2T_BLOCKS + 3 * GEMM1_BLOCKS)   // 8 + 4689 = 4697

// ---------------------------------------------------------------------------
// Fused front kernel. Role by blockIdx:
//   [0,8)            : W2 -> W2t fp16 transpose-convert (for MFMA gemm2)
//   rem==0 of rest   : gemm1 fp32 (x @ W1 -> bufA fp16), VALU-bound
//   rem==1,2         : bucket_edges (atomic-bound, VALU ~0) -- co-scheduled
// ---------------------------------------------------------------------------
__global__ __launch_bounds__(256) void front(const float* __restrict__ x,
                                             const float* __restrict__ W1,
                                             u16* __restrict__ bufA,
                                             const int* __restrict__ src,
                                             const int* __restrict__ dst,
                                             int* __restrict__ deg,
                                             u16* __restrict__ epad,
                                             const float* __restrict__ W2,
                                             u16* __restrict__ W2t)
{
    __shared__ float xs[32][36];
    __shared__ float ws[32][128];
    const int tid = threadIdx.x;
    int bid = blockIdx.x;

    if (bid < W2T_BLOCKS) {
        // W2t[n][k] = fp16(W2[k][n]); 16384 elems over 2048 threads
        int t0 = bid * 256 + tid;
        for (int i = t0; i < HDIM * HDIM; i += W2T_BLOCKS * 256) {
            int k = i >> 7, n = i & 127;
            W2t[n * HDIM + k] = f2h(W2[i]);
        }
        return;
    }
    bid -= W2T_BLOCKS;
    const int grp = bid / 3, rem = bid % 3;

    if (rem != 0) {
        // ---- bucket_edges ----
        int e = (grp * 2 + (rem - 1)) * 256 + tid;
        if (e < N_EDGES) {
            int d   = dst[e];
            int pos = atomicAdd(&deg[d], 1);
            epad[d * MAXDEG + pos] = (u16)src[e];
        }
        return;
    }

    // ---- gemm1: 32 rows, fp32 VALU, 4x4 register tile ----
    const int row0 = grp * 32;
    const int tx   = tid & 31;
    const int ty   = tid >> 5;

    float acc[4][4];
    #pragma unroll
    for (int i = 0; i < 4; ++i)
        #pragma unroll
        for (int j = 0; j < 4; ++j) acc[i][j] = 0.f;

    const int lr = tid >> 3;
    const int lk = (tid & 7) << 2;
    const int wr = tid >> 5;
    const int wc = (tid & 31) << 2;

    for (int k0 = 0; k0 < 128; k0 += 32) {
        float4 xv = make_float4(0.f, 0.f, 0.f, 0.f);
        int grow = row0 + lr;
        if (grow < N_NODES) xv = *(const float4*)(x + (size_t)grow * HDIM + k0 + lk);
        xs[lr][lk] = xv.x; xs[lr][lk + 1] = xv.y; xs[lr][lk + 2] = xv.z; xs[lr][lk + 3] = xv.w;
        #pragma unroll
        for (int i = 0; i < 4; ++i) {
            int kk = wr + i * 8;
            *(float4*)&ws[kk][wc] = *(const float4*)(W1 + (size_t)(k0 + kk) * HDIM + wc);
        }
        __syncthreads();
        #pragma unroll
        for (int kk = 0; kk < 32; kk += 4) {
            float4 wv[4];
            #pragma unroll
            for (int j = 0; j < 4; ++j) wv[j] = *(const float4*)&ws[kk + j][tx << 2];
            #pragma unroll
            for (int i = 0; i < 4; ++i) {
                float4 xr = *(const float4*)&xs[ty * 4 + i][kk];
                acc[i][0] += xr.x * wv[0].x; acc[i][1] += xr.x * wv[0].y;
                acc[i][2] += xr.x * wv[0].z; acc[i][3] += xr.x * wv[0].w;
                acc[i][0] += xr.y * wv[1].x; acc[i][1] += xr.y * wv[1].y;
                acc[i][2] += xr.y * wv[1].z; acc[i][3] += xr.y * wv[1].w;
                acc[i][0] += xr.z * wv[2].x; acc[i][1] += xr.z * wv[2].y;
                acc[i][2] += xr.z * wv[2].z; acc[i][3] += xr.z * wv[2].w;
                acc[i][0] += xr.w * wv[3].x; acc[i][1] += xr.w * wv[3].y;
                acc[i][2] += xr.w * wv[3].z; acc[i][3] += xr.w * wv[3].w;
            }
        }
        __syncthreads();
    }
    #pragma unroll
    for (int i = 0; i < 4; ++i) {
        int grow = row0 + ty * 4 + i;
        if (grow < N_NODES) {
            uint2 o;
            o.x = packh2(acc[i][0], acc[i][1]);
            o.y = packh2(acc[i][2], acc[i][3]);
            *(uint2*)(bufA + (size_t)grow * HDIM + (tx << 2)) = o;
        }
    }
}

// ---------------------------------------------------------------------------
// Layer-2 GEMM via fp16 MFMA 16x16x32.  Y[n][:] = A[n][:] @ W2  (A,Y fp16).
// W2t is pre-transposed fp16 [n][k].  Block: 256 thr = 4 waves x 16 rows.
// B staged in LDS, stride 144 (slot-uniform for ds_read_b128);
// A-fragments straight from global (16B/lane, sector-coalesced).
// ---------------------------------------------------------------------------
#define BT_STRIDE 144
__global__ __launch_bounds__(256) void gemm2_mfma(const u16* __restrict__ A,
                                                  const u16* __restrict__ W2t,
                                                  u16* __restrict__ Y, int nrows)
{
    __shared__ u16 bt[HDIM * BT_STRIDE];
    const int tid = threadIdx.x;
    // stage W2t (dense 128x128 fp16) -> LDS stride 144, vectorized 16B
    for (int i = tid; i < HDIM * HDIM / 8; i += 256) {
        int n  = i >> 4;
        int k8 = (i & 15) << 3;
        *(uint4*)&bt[n * BT_STRIDE + k8] = *(const uint4*)&W2t[n * HDIM + k8];
    }
    __syncthreads();

    const int wave = tid >> 6, lane = tid & 63;
    const int rowbase = blockIdx.x * 64 + wave * 16;
    if (rowbase >= nrows) return;                   // 50000 % 16 == 0: whole strips
    const int n = lane & 15, q = lane >> 4;

    half8 a[4];
    const u16* arow = A + (size_t)(rowbase + n) * HDIM;
    #pragma unroll
    for (int kc = 0; kc < 4; ++kc)
        a[kc] = *(const half8*)(arow + kc * 32 + q * 8);

    #pragma unroll
    for (int t = 0; t < 8; ++t) {
        f32x4 acc = {0.f, 0.f, 0.f, 0.f};
        #pragma unroll
        for (int kc = 0; kc < 4; ++kc) {
            half8 b = *(const half8*)&bt[(t * 16 + n) * BT_STRIDE + kc * 32 + q * 8];
            acc = __builtin_amdgcn_mfma_f32_16x16x32_f16(a[kc], b, acc, 0, 0, 0);
        }
        #pragma unroll
        for (int r = 0; r < 4; ++r) {
            int grow = rowbase + q * 4 + r;          // C/D: col=lane&15, row=quad*4+reg
            Y[(size_t)grow * HDIM + t * 16 + n] = f2h(acc[r]);
        }
    }
}

// ---------------------------------------------------------------------------
// Padded-bucket gather + self-loop + bias + BN(eval) + ReLU, fused. fp16 h.
// One node/wave; quarter-wave per edge (lane: 8 channels, 16B load);
// 2x unrolled (8 edges in flight); per-edge rsqrt fused (no dis array).
// ---------------------------------------------------------------------------
__global__ __launch_bounds__(256) void gather_bn_relu(const u16* __restrict__ h,
                                                      const u16* __restrict__ epad,
                                                      const int* __restrict__ deg,
                                                      const float* __restrict__ b,
                                                      const float* __restrict__ gamma,
                                                      const float* __restrict__ beta,
                                                      const float* __restrict__ mean,
                                                      const float* __restrict__ var,
                                                      u16* __restrict__ out, int n)
{
    int node = blockIdx.x * 4 + (threadIdx.x >> 6);
    if (node >= n) return;
    const int lane = threadIdx.x & 63;
    const int q    = lane >> 4;          // quarter: which edge of the 4
    const int ci   = (lane & 15) << 3;   // 8 channels per lane
    const int cnt_e = deg[node];
    const float dd  = rsqrtf((float)cnt_e + 1.0f);

    // self-row load early (independent, hides latency)
    uint4 hv = *(const uint4*)(h + (size_t)node * HDIM + ci);

    // preload this node's edge list: lane l owns edge l (cnt_e <= 64)
    int   s_all  = 0;
    float nm_all = 0.f;
    if (lane < cnt_e) {
        s_all  = epad[node * MAXDEG + lane];
        nm_all = rsqrtf((float)deg[s_all] + 1.0f) * dd;
    }

    float acc[8] = {0.f, 0.f, 0.f, 0.f, 0.f, 0.f, 0.f, 0.f};
    int j = q;
    for (; j + 4 < cnt_e; j += 8) {
        int   s0 = __shfl(s_all, j);     float nm0 = __shfl(nm_all, j);
        int   s1 = __shfl(s_all, j + 4); float nm1 = __shfl(nm_all, j + 4);
        uint4 v0 = *(const uint4*)(h + (size_t)s0 * HDIM + ci);
        uint4 v1 = *(const uint4*)(h + (size_t)s1 * HDIM + ci);
        float2 f0 = h2f2(v0.x), f1 = h2f2(v0.y), f2 = h2f2(v0.z), f3 = h2f2(v0.w);
        acc[0] += f0.x * nm0; acc[1] += f0.y * nm0;
        acc[2] += f1.x * nm0; acc[3] += f1.y * nm0;
        acc[4] += f2.x * nm0; acc[5] += f2.y * nm0;
        acc[6] += f3.x * nm0; acc[7] += f3.y * nm0;
        float2 g0 = h2f2(v1.x), g1 = h2f2(v1.y), g2 = h2f2(v1.z), g3 = h2f2(v1.w);
        acc[0] += g0.x * nm1; acc[1] += g0.y * nm1;
        acc[2] += g1.x * nm1; acc[3] += g1.y * nm1;
        acc[4] += g2.x * nm1; acc[5] += g2.y * nm1;
        acc[6] += g3.x * nm1; acc[7] += g3.y * nm1;
    }
    if (j < cnt_e) {
        int   s0 = __shfl(s_all, j); float nm0 = __shfl(nm_all, j);
        uint4 v0 = *(const uint4*)(h + (size_t)s0 * HDIM + ci);
        float2 f0 = h2f2(v0.x), f1 = h2f2(v0.y), f2 = h2f2(v0.z), f3 = h2f2(v0.w);
        acc[0] += f0.x * nm0; acc[1] += f0.y * nm0;
        acc[2] += f1.x * nm0; acc[3] += f1.y * nm0;
        acc[4] += f2.x * nm0; acc[5] += f2.y * nm0;
        acc[6] += f3.x * nm0; acc[7] += f3.y * nm0;
    }
    #pragma unroll
    for (int k = 0; k < 8; ++k) {
        acc[k] += __shfl_xor(acc[k], 16);
        acc[k] += __shfl_xor(acc[k], 32);
    }

    if (q == 0) {
        float2 g0 = h2f2(hv.x), g1 = h2f2(hv.y), g2 = h2f2(hv.z), g3 = h2f2(hv.w);
        float dd2 = dd * dd;
        float a[8] = {acc[0] + g0.x * dd2, acc[1] + g0.y * dd2,
                      acc[2] + g1.x * dd2, acc[3] + g1.y * dd2,
                      acc[4] + g2.x * dd2, acc[5] + g2.y * dd2,
                      acc[6] + g3.x * dd2, acc[7] + g3.y * dd2};
        float o[8];
        #pragma unroll
        for (int k = 0; k < 8; ++k) {
            int c = ci + k;
            float sc = gamma[c] * rsqrtf(var[c] + BN_EPS);
            float r  = (a[k] + b[c] - mean[c]) * sc + beta[c];
            o[k] = fmaxf(r, 0.f);
        }
        uint4 ov;
        ov.x = packh2(o[0], o[1]); ov.y = packh2(o[2], o[3]);
        ov.z = packh2(o[4], o[5]); ov.w = packh2(o[6], o[7]);
        *(uint4*)(out + (size_t)node * HDIM + ci) = ov;
    }
}

// ---------------------------------------------------------------------------
// Pool: sums[batch[n]][c] += h[n][c] (fp16 h, fp32 sums); batch sorted.
// Also accumulates per-graph node counts (thread 0 of each block).
// ---------------------------------------------------------------------------
__global__ __launch_bounds__(128) void pool_sum(const u16* __restrict__ h,
                                                const int* __restrict__ batch,
                                                float* __restrict__ sums,
                                                float* __restrict__ cnt, int n)
{
    int c  = threadIdx.x;
    int n0 = blockIdx.x * 32;
    if (n0 >= n) return;
    int nend = min(n0 + 32, n);
    int curg = batch[n0];
    float acc = 0.f;
    int run = 0;
    for (int i = n0; i < nend; ++i) {
        int g   = batch[i];
        float v = __half2float(__ushort_as_half(h[(size_t)i * HDIM + c]));
        if (g != curg) {
            atomicAdd(&sums[(size_t)curg * HDIM + c], acc);
            if (c == 0) atomicAdd(&cnt[curg], (float)run);
            acc = 0.f; run = 0; curg = g;
        }
        acc += v; run++;
    }
    atomicAdd(&sums[(size_t)curg * HDIM + c], acc);
    if (c == 0) atomicAdd(&cnt[curg], (float)run);
}

// ---------------------------------------------------------------------------
// out[g][c] = (sums[g]/max(cnt[g],1)) . Wlin[:,c] + blin[c]
// ---------------------------------------------------------------------------
__global__ __launch_bounds__(128) void final_lin(const float* __restrict__ sums,
                                                 const float* __restrict__ cnt,
                                                 const float* __restrict__ Wlin,
                                                 const float* __restrict__ blin,
                                                 float* __restrict__ out)
{
    __shared__ float red[NCLS][2];
    int g = blockIdx.x;
    int t = threadIdx.x;
    float ic = 1.f / fmaxf(cnt[g], 1.f);
    float v  = sums[(size_t)g * HDIM + t] * ic;
    float p[NCLS];
    #pragma unroll
    for (int c = 0; c < NCLS; ++c) p[c] = v * Wlin[t * NCLS + c];
    #pragma unroll
    for (int c = 0; c < NCLS; ++c) {
        float x = p[c];
        for (int off = 32; off > 0; off >>= 1) x += __shfl_down(x, off);
        if ((t & 63) == 0) red[c][t >> 6] = x;
    }
    __syncthreads();
    if (t < NCLS) out[g * NCLS + t] = red[t][0] + red[t][1] + blin[t];
}

// ---------------------------------------------------------------------------
extern "C" void kernel_launch(void* const* d_in, const int* in_sizes, int n_in,
                              void* d_out, int out_size, void* d_ws, size_t ws_size,
                              hipStream_t stream)
{
    const float* x     = (const float*)d_in[0];
    const int*   ei    = (const int*)d_in[1];
    const int*   srcp  = ei;
    const int*   dstp  = ei + N_EDGES;
    const int*   batch = (const int*)d_in[2];
    const float* W1    = (const float*)d_in[3];
    const float* b1    = (const float*)d_in[4];
    const float* g1    = (const float*)d_in[5];
    const float* be1   = (const float*)d_in[6];
    const float* m1    = (const float*)d_in[7];
    const float* v1    = (const float*)d_in[8];
    const float* W2    = (const float*)d_in[9];
    const float* b2    = (const float*)d_in[10];
    const float* g2    = (const float*)d_in[11];
    const float* be2   = (const float*)d_in[12];
    const float* m2    = (const float*)d_in[13];
    const float* v2    = (const float*)d_in[14];
    const float* Wlin  = (const float*)d_in[15];
    const float* blin  = (const float*)d_in[16];
    float*       out   = (float*)d_out;

    // workspace layout (~32.5 MiB):
    // [deg int | cnt f32 | sums f32]  <- one contiguous zeroed region
    // bufA fp16 | bufB fp16 | epad u16 | W2t fp16
    int*   deg  = (int*)d_ws;
    float* cnt  = (float*)(deg + N_NODES);
    float* sums = cnt + NGRAPH;
    u16*   bufA = (u16*)(sums + (size_t)NGRAPH * HDIM);
    u16*   bufB = bufA + (size_t)N_NODES * HDIM;
    u16*   epad = bufB + (size_t)N_NODES * HDIM;
    u16*   W2t  = epad + (size_t)N_NODES * MAXDEG;

    hipMemsetAsync(deg, 0,
                   (N_NODES + NGRAPH + (size_t)NGRAPH * HDIM) * sizeof(float), stream);

    // ---- fused front: bucket + gemm1 + W2 transpose ----
    front<<<FRONT_GRID, 256, 0, stream>>>(x, W1, bufA, srcp, dstp, deg, epad, W2, W2t);

    const int gather_blocks = (N_NODES + 3) / 4;

    // ---- layer 1 aggregation ----
    gather_bn_relu<<<gather_blocks, 256, 0, stream>>>(bufA, epad, deg,
                                                      b1, g1, be1, m1, v1, bufB, N_NODES);
    // ---- layer 2 ----
    gemm2_mfma<<<(N_NODES + 63) / 64, 256, 0, stream>>>(bufB, W2t, bufA, N_NODES);
    gather_bn_relu<<<gather_blocks, 256, 0, stream>>>(bufA, epad, deg,
                                                      b2, g2, be2, m2, v2, bufB, N_NODES);
    // ---- pool + head ----
    pool_sum<<<(N_NODES + 31) / 32, 128, 0, stream>>>(bufB, batch, sums, cnt, N_NODES);
    final_lin<<<NGRAPH, 128, 0, stream>>>(sums, cnt, Wlin, blin, out);
}